// Round 15
// baseline (22.635 us; speedup 1.0000x reference)
//
#include <hip/hip_runtime.h>
#include <stdint.h>
#include <math.h>

#define NB 8
#define NN 128
#define NC 64
#define DEG 10
#define HP (DEG / 2)
#define NUM_STEPS 5

typedef float v2f __attribute__((ext_vector_type(2)));

__device__ __forceinline__ v2f mk2(float x, float y) { v2f r; r.x = x; r.y = y; return r; }
__device__ __forceinline__ v2f splat2(float x)       { v2f r; r.x = x; r.y = x; return r; }
__device__ __forceinline__ v2f pfma(v2f a, v2f b, v2f c) {
    return __builtin_elementwise_fma(a, b, c);     // -> v_pk_fma_f32 on gfx950
}

// DPP lane swaps within a quad (pure VALU, no LDS pipe, convergent callers).
__device__ __forceinline__ float pswap(float x) {   // lanes 2k <-> 2k+1
    return __int_as_float(__builtin_amdgcn_update_dpp(
        0, __float_as_int(x), 0xB1, 0xF, 0xF, false));
}
__device__ __forceinline__ float pswap2(float x) {  // quad_perm [2,3,0,1]
    return __int_as_float(__builtin_amdgcn_update_dpp(
        0, __float_as_int(x), 0x4E, 0xF, 0xF, false));
}
// DPP with 0-fill out-of-bounds: safe for SUM reductions (adds 0).
template<int C>
__device__ __forceinline__ float dpp0(float x) {
    return __int_as_float(__builtin_amdgcn_update_dpp(
        0, __float_as_int(x), C, 0xF, 0xF, true));
}

// ---------------------------------------------------------------------------
// Single fused kernel. Block = (b,i), 256 threads. R14 structure with the
// SIM row loop made STRAIGHT-LINE BRANCHLESS: xsl rows r>=dsi are zero-filled
// at staging, the exp result is selected against 0 (cndmask) instead of
// branching, and the self row is peeled. This removes the per-row uniform
// branches that blocked the scheduler from hoisting ds_reads across rows
// (the sim phase was serializing read->fma->reduce->exp per row). Stored
// values are bit-identical (invalid rows still write exact 0).
//
// SIM phase: thread (jp = tid>>2, qh = tid&3) owns a QUARTER of x_t rows
// 2jp, 2jp+1 packed as v2f xvp[16]; broadcast-reads each xsl[r] quarter,
// 16 packed FMAs per row; 2-step DPP butterfly per component; qh==0/1 write
// cols 2jp/2jp+1. exp(sim) stored TRANSPOSED: ecol[col][slot], slot(r) =
// r + (r>=5 ? 3 : 0) (16B-aligned b128 at slots 0/8). Col NN all-zero ->
// T-gather needs no mask. Raw sim recovered as ln(T); self row in ssim[].
//
// SINKHORN: j = tid>>1, h = tid&1; rank-factored S[p][q] ==
// T[p][q]*a[p]*b[q], T = exp(S_hat) (exp monotone + row-softmax normalizes
// => max-subtraction unnecessary; |sim| <~ 45 keeps products finite).
// T packed by q-pairs at the gather. Thread h owns rows h*5..h*5+4; col
// sums split p-wise, combined via DPP per component; b/a updates
// unpredicated (masked lanes self-preserve: 0*rcp(1e-8)==0). Loop is
// 4x(col+row) + 1 final col (last row phase is dead: the final row
// normalization scales each row by a positive constant -> row-argmax
// invariant; cost reads raw S_hat). argmax products packed (v_pk_mul),
// compare order x-then-y per pair == exact q order, strict > keeps first
// max; q=0 always valid (deg>=1), valid entries strictly positive -> zero
// slots never win. cost = ln(T[best]) via __logf (roundtrip ~5e-6 << bf16
// output granularity).
// Tail: ONE barrier — wave max via shfl butterfly, wave sum via DPP
// shr/bcast tree (lane 63 writes); block combine ssum[w]*exp(smax[w]-bm);
// each pair's v appears twice -> *0.5.
// ---------------------------------------------------------------------------
__global__ __launch_bounds__(256, 4) void fused_kernel(
    const float* __restrict__ xs, const float* __restrict__ xt,
    const int* __restrict__ dst_s, const int* __restrict__ dst_t,
    float* __restrict__ out)
{
    __shared__ float  ssim[NN];              // self sim row (for epilogue)
    __shared__ float  ecol[NN + 1][20];      // transposed exp rows; col NN zero
    __shared__ float4 xsl[DEG + 1][NC / 4];
    __shared__ float  smax[4], ssum[4];

    const int bi  = blockIdx.x;
    const int b   = bi >> 7, i = bi & 127;
    const int tid = threadIdx.x;
    const int gs  = b * NN + i;

    // ---- s-side neighbor mask (block-uniform) ----
    unsigned long long slo = 0ull, shi = 0ull;
    #pragma unroll
    for (int k = 0; k < DEG; ++k) {
        int d = dst_s[gs * DEG + k] & (NN - 1);
        if (d < 64) slo |= 1ull << d; else shi |= 1ull << (d - 64);
    }
    const int dsi = __popcll(slo) + __popcll(shi);

    // ---- sim-phase mapping: quarter-row, two columns per thread (packed) ----
    const int qh = tid & 3;                  // quarter id
    const int jp = tid >> 2;                 // column pair 0..63
    const int c0 = 2 * jp;                   // owned columns c0, c0+1
    v2f xvp[16];
    {
        const float4* xt0 = (const float4*)(xt + (size_t)(b * NN + c0)     * NC) + qh * 4;
        const float4* xt1 = (const float4*)(xt + (size_t)(b * NN + c0 + 1) * NC) + qh * 4;
        #pragma unroll
        for (int k = 0; k < 4; ++k) {
            float4 u = xt0[k], w = xt1[k];
            xvp[4 * k + 0] = mk2(u.x, w.x);
            xvp[4 * k + 1] = mk2(u.y, w.y);
            xvp[4 * k + 2] = mk2(u.z, w.z);
            xvp[4 * k + 3] = mk2(u.w, w.w);
        }
    }

    // ---- zero column of ecol (slots 0..12 cover all read slots) ----
    if (tid < 13) ecol[NN][tid] = 0.0f;

    // ---- stage x_s rows into LDS (rows >= dsi ZERO-FILLED -> sim loop is
    //      branchless): threads 0..175, row = tid>>4, k = tid&15 ----
    if (tid < (DEG + 1) * 16) {
        int r = tid >> 4, k = tid & 15;
        int node = i;                        // r==10 -> self row
        if (r < DEG) {
            unsigned long long lo = slo, hi = shi; int sel = 0;
            #pragma unroll
            for (int q = 0; q < DEG; ++q) {  // static walk, scalar select
                int t;
                if (lo)      { t = __builtin_ctzll(lo);      lo &= lo - 1ull; }
                else if (hi) { t = 64 + __builtin_ctzll(hi); hi &= hi - 1ull; }
                else t = 0;
                if (q == r) sel = t;
            }
            node = sel;
        }
        float4 val = ((const float4*)(xs + (size_t)(b * NN + node) * NC))[k];
        float4 z;  z.x = 0.f; z.y = 0.f; z.z = 0.f; z.w = 0.f;
        xsl[r][k] = (r == DEG || r < dsi) ? val : z;
    }

    // ---- t-side neighbor list for sinkhorn pair j = tid>>1 (int2 loads) ----
    const int j = tid >> 1, h = tid & 1;
    const int gt = b * NN + j;
    unsigned long long tlo = 0ull, thi = 0ull;
    {
        const int2* dt2 = (const int2*)(dst_t + (size_t)gt * DEG);  // 40B rows, 8B-aligned
        int2 w0 = dt2[0], w1 = dt2[1], w2 = dt2[2], w3 = dt2[3], w4 = dt2[4];
        int dd[DEG] = { w0.x, w0.y, w1.x, w1.y, w2.x, w2.y, w3.x, w3.y, w4.x, w4.y };
        #pragma unroll
        for (int k = 0; k < DEG; ++k) {      // static-indexed reads of dd
            int dm = dd[k] & (NN - 1);
            if (dm < 64) tlo |= 1ull << dm; else thi |= 1ull << (dm - 64);
        }
    }
    const int dtj = __popcll(tlo) + __popcll(thi);
    int ntq[DEG];
    {
        unsigned long long lo = tlo, hi = thi;
        #pragma unroll
        for (int q = 0; q < DEG; ++q) {      // static-indexed writes
            int t;
            if (lo)      { t = __builtin_ctzll(lo);      lo &= lo - 1ull; }
            else if (hi) { t = 64 + __builtin_ctzll(hi); hi &= hi - 1ull; }
            else t = 0;
            ntq[q] = (q < dtj) ? t : NN;     // invalid -> zero column
        }
    }
    __syncthreads();

    // ---- sim dots: BRANCHLESS row loop (scheduler can hoist ds_reads) ----
    #pragma unroll
    for (int r = 0; r < DEG; ++r) {
        v2f acc = mk2(0.f, 0.f);
        #pragma unroll
        for (int k = 0; k < 4; ++k) {
            float4 s4 = xsl[r][qh * 4 + k];
            acc = pfma(splat2(s4.x), xvp[4 * k + 0], acc);
            acc = pfma(splat2(s4.y), xvp[4 * k + 1], acc);
            acc = pfma(splat2(s4.z), xvp[4 * k + 2], acc);
            acc = pfma(splat2(s4.w), xvp[4 * k + 3], acc);
        }
        float a0 = acc.x, a1 = acc.y;
        // 4-lane butterfly: all lanes end with the full deterministic sum
        a0 += pswap(a0);  a0 += pswap2(a0);
        a1 += pswap(a1);  a1 += pswap2(a1);
        float vv = (qh & 1) ? a1 : a0;
        float ev = (r < dsi) ? __expf(vv) : 0.0f;   // cndmask, no branch
        if (qh < 2) ecol[c0 + (qh & 1)][r + ((r >= HP) ? 3 : 0)] = ev;
    }
    {   // self row (peeled)
        v2f acc = mk2(0.f, 0.f);
        #pragma unroll
        for (int k = 0; k < 4; ++k) {
            float4 s4 = xsl[DEG][qh * 4 + k];
            acc = pfma(splat2(s4.x), xvp[4 * k + 0], acc);
            acc = pfma(splat2(s4.y), xvp[4 * k + 1], acc);
            acc = pfma(splat2(s4.z), xvp[4 * k + 2], acc);
            acc = pfma(splat2(s4.w), xvp[4 * k + 3], acc);
        }
        float a0 = acc.x, a1 = acc.y;
        a0 += pswap(a0);  a0 += pswap2(a0);
        a1 += pswap(a1);  a1 += pswap2(a1);
        float vv = (qh & 1) ? a1 : a0;
        if (qh < 2) ssim[c0 + (qh & 1)] = vv;
    }
    __syncthreads();

    // ---- gather own half of T, packed by q-pairs straight from LDS ----
    v2f T2[HP][5];                           // T2[pp][qq] = (T[pp][2qq], T[pp][2qq+1])
    float a[HP];
    v2f bv2[5];
    #pragma unroll
    for (int qq = 0; qq < 5; ++qq)
        bv2[qq] = mk2((2 * qq < dtj) ? 1.0f : 0.0f, (2 * qq + 1 < dtj) ? 1.0f : 0.0f);

    const int sbase = h << 3;                // h=0 -> slots 0..4; h=1 -> 8..12
    #pragma unroll
    for (int qq = 0; qq < 5; ++qq) {
        const float* cp0 = &ecol[ntq[2 * qq]][sbase];
        const float* cp1 = &ecol[ntq[2 * qq + 1]][sbase];
        float4 A4 = *(const float4*)cp0;     // ds_read_b128
        float  Ae = cp0[4];                  // ds_read_b32
        float4 B4 = *(const float4*)cp1;
        float  Be = cp1[4];
        T2[0][qq] = mk2(A4.x, B4.x);
        T2[1][qq] = mk2(A4.y, B4.y);
        T2[2][qq] = mk2(A4.z, B4.z);
        T2[3][qq] = mk2(A4.w, B4.w);
        T2[4][qq] = mk2(Ae,   Be);
    }
    #pragma unroll
    for (int pp = 0; pp < HP; ++pp) {
        int p = h * HP + pp;
        v2f s01 = T2[pp][0] + T2[pp][1];
        v2f s23 = T2[pp][2] + T2[pp][3];
        v2f s   = (s01 + s23) + T2[pp][4];
        float sum = s.x + s.y;
        a[pp] = (p < dsi) ? __builtin_amdgcn_rcpf(sum) * 10.0f : 0.0f;
    }

    // ---- Sinkhorn: 4 x (col + row) + final col (last row phase is dead) ----
#define COL_PHASE()                                                            \
    {                                                                          \
        _Pragma("unroll")                                                      \
        for (int qq = 0; qq < 5; ++qq) {                                       \
            v2f cA = pfma(splat2(a[2]), T2[2][qq],                             \
                      pfma(splat2(a[1]), T2[1][qq], T2[0][qq] * splat2(a[0])));\
            v2f cB = pfma(splat2(a[4]), T2[4][qq], T2[3][qq] * splat2(a[3]));  \
            v2f c  = cA + cB;                                                  \
            float cx = c.x + pswap(c.x);     /* identical on both lanes */     \
            float cy = c.y + pswap(c.y);                                       \
            float b0 = bv2[qq].x, b1 = bv2[qq].y;                              \
            /* masked q: b==0 -> 0 * rcp(1e-8) == 0 exactly */                 \
            bv2[qq].x = b0 * __builtin_amdgcn_rcpf(fmaf(b0, cx, 1e-8f));       \
            bv2[qq].y = b1 * __builtin_amdgcn_rcpf(fmaf(b1, cy, 1e-8f));       \
        }                                                                      \
    }

    #pragma unroll 1
    for (int it = 0; it < NUM_STEPS - 1; ++it) {
        COL_PHASE()
        // row phase: packed q-pair chains + horizontal add
        #pragma unroll
        for (int pp = 0; pp < HP; ++pp) {
            v2f r1 = pfma(T2[pp][1], bv2[1], T2[pp][0] * bv2[0]);
            v2f r2 = pfma(T2[pp][3], bv2[3], T2[pp][2] * bv2[2]);
            v2f rr = pfma(T2[pp][4], bv2[4], r1 + r2);
            float r = rr.x + rr.y;
            float ap = a[pp];
            // masked row: ap==0 and r==0 -> 0 * rcp(1e-8) == 0 exactly
            a[pp] = ap * __builtin_amdgcn_rcpf(fmaf(ap, r, 1e-8f));
        }
    }
    COL_PHASE()                               // 5th col; 5th row phase dead
#undef COL_PHASE

    // ---- argmax per own row over T*b (packed muls, exact q order) ----
    float cpart = 0.f;
    #pragma unroll
    for (int pp = 0; pp < HP; ++pp) {
        int p = h * HP + pp;
        if (p < dsi) {
            v2f pr0 = T2[pp][0] * bv2[0];
            v2f pr1 = T2[pp][1] * bv2[1];
            v2f pr2 = T2[pp][2] * bv2[2];
            v2f pr3 = T2[pp][3] * bv2[3];
            v2f pr4 = T2[pp][4] * bv2[4];
            float best = pr0.x;               // q=0 always valid (deg>=1)
            float bT   = T2[pp][0].x;
            if (pr0.y > best) { best = pr0.y; bT = T2[pp][0].y; }
            if (pr1.x > best) { best = pr1.x; bT = T2[pp][1].x; }
            if (pr1.y > best) { best = pr1.y; bT = T2[pp][1].y; }
            if (pr2.x > best) { best = pr2.x; bT = T2[pp][2].x; }
            if (pr2.y > best) { best = pr2.y; bT = T2[pp][2].y; }
            if (pr3.x > best) { best = pr3.x; bT = T2[pp][3].x; }
            if (pr3.y > best) { best = pr3.y; bT = T2[pp][3].y; }
            if (pr4.x > best) { best = pr4.x; bT = T2[pp][4].x; }
            if (pr4.y > best) { best = pr4.y; bT = T2[pp][4].y; }
            cpart += __logf(bT);              // == sim value (roundtrip ~5e-6)
        }
    }
    float cost = cpart + pswap(cpart);           // identical on both lanes

    float M = (float)((dsi > dtj) ? dsi : dtj);
    float simv = ssim[j];
    float v = fmaf(cost, __builtin_amdgcn_rcpf(1.0f + M), simv);

    // ---- one-barrier block softmax over j (each pair's v counted twice) ----
    float wm = v;                                // wave max: all lanes need it
    #pragma unroll
    for (int off = 32; off; off >>= 1) wm = fmaxf(wm, __shfl_xor(wm, off));
    float ew = __expf(v - wm);
    // wave sum via DPP tree (0-fill OOB); total lands on lane 63
    float ws = ew;
    ws += dpp0<0x111>(ws);                       // row_shr:1
    ws += dpp0<0x112>(ws);                       // row_shr:2
    ws += dpp0<0x114>(ws);                       // row_shr:4
    ws += dpp0<0x118>(ws);                       // row_shr:8
    ws += dpp0<0x142>(ws);                       // row_bcast15
    ws += dpp0<0x143>(ws);                       // row_bcast31
    int wsl = tid >> 6;
    if ((tid & 63) == 63) { smax[wsl] = wm; ssum[wsl] = ws; }
    __syncthreads();
    float bm = fmaxf(fmaxf(smax[0], smax[1]), fmaxf(smax[2], smax[3]));
    float bs = (ssum[0] * __expf(smax[0] - bm) + ssum[1] * __expf(smax[1] - bm) +
                ssum[2] * __expf(smax[2] - bm) + ssum[3] * __expf(smax[3] - bm)) * 0.5f;
    float e = ew * __expf(wm - bm);

    if (h == 0) out[(size_t)gs * NN + j] = e * __builtin_amdgcn_rcpf(bs);
}

// ---------------------------------------------------------------------------
extern "C" void kernel_launch(void* const* d_in, const int* in_sizes, int n_in,
                              void* d_out, int out_size, void* d_ws, size_t ws_size,
                              hipStream_t stream) {
    (void)in_sizes; (void)n_in; (void)out_size; (void)d_ws; (void)ws_size;
    const float* x_s  = (const float*)d_in[0];
    const int*   ei_s = (const int*)  d_in[1];
    const float* x_t  = (const float*)d_in[3];
    const int*   ei_t = (const int*)  d_in[4];
    float* out = (float*)d_out;

    const int* dst_s = ei_s + NB * NN * DEG;   // second row of edge_index
    const int* dst_t = ei_t + NB * NN * DEG;

    hipLaunchKernelGGL(fused_kernel, dim3(NB * NN), dim3(256), 0, stream,
                       x_s, x_t, dst_s, dst_t, out);
}

// Round 16
// 21.284 us; speedup vs baseline: 1.0635x; 1.0635x over previous
//
#include <hip/hip_runtime.h>
#include <stdint.h>
#include <math.h>

#define NB 8
#define NN 128
#define NC 64
#define DEG 10
#define HP (DEG / 2)
#define NUM_STEPS 5

typedef float v2f __attribute__((ext_vector_type(2)));

__device__ __forceinline__ v2f mk2(float x, float y) { v2f r; r.x = x; r.y = y; return r; }
__device__ __forceinline__ v2f splat2(float x)       { v2f r; r.x = x; r.y = x; return r; }
__device__ __forceinline__ v2f pfma(v2f a, v2f b, v2f c) {
    return __builtin_elementwise_fma(a, b, c);     // -> v_pk_fma_f32 on gfx950
}

// DPP lane swaps within a quad (pure VALU, no LDS pipe, convergent callers).
__device__ __forceinline__ float pswap(float x) {   // lanes 2k <-> 2k+1
    return __int_as_float(__builtin_amdgcn_update_dpp(
        0, __float_as_int(x), 0xB1, 0xF, 0xF, false));
}
__device__ __forceinline__ float pswap2(float x) {  // quad_perm [2,3,0,1]
    return __int_as_float(__builtin_amdgcn_update_dpp(
        0, __float_as_int(x), 0x4E, 0xF, 0xF, false));
}
// DPP with 0-fill out-of-bounds: safe for SUM reductions (adds 0).
template<int C>
__device__ __forceinline__ float dpp0(float x) {
    return __int_as_float(__builtin_amdgcn_update_dpp(
        0, __float_as_int(x), C, 0xF, 0xF, true));
}

// ---------------------------------------------------------------------------
// Single fused kernel (R14 revert — best measured: 21.4 us). Block = (b,i),
// 256 threads.
//
// SIM phase: thread (jp = tid>>2, qh = tid&3) owns a QUARTER of x_t rows
// 2jp, 2jp+1 packed as v2f xvp[16]; broadcast-reads each xsl[r] quarter,
// 16 packed FMAs per row (wave-uniform r<dsi guard); 2-step DPP butterfly
// per component; qh==0/1 write cols 2jp/2jp+1. exp(sim) stored TRANSPOSED:
// ecol[col][slot], slot(r) = r + (r>=5 ? 3 : 0) (16B-aligned b128 at slots
// 0/8). Rows p>=dsi zeroed; col NN all-zero -> T-gather needs no mask.
// Raw sim recovered as ln(T); self row in ssim[].
//
// SINKHORN: j = tid>>1, h = tid&1; rank-factored S[p][q] ==
// T[p][q]*a[p]*b[q], T = exp(S_hat) (exp monotone + row-softmax normalizes
// => max-subtraction unnecessary; |sim| <~ 45 keeps products finite).
// T packed by q-pairs at the gather. Thread h owns rows h*5..h*5+4; col
// sums split p-wise, combined via DPP per component; b/a updates
// unpredicated (masked lanes self-preserve: 0*rcp(1e-8)==0). Loop is
// 4x(col+row) + 1 final col (last row phase dead: final row normalization
// scales rows by positive constants -> row-argmax invariant; cost reads raw
// S_hat). argmax products packed (v_pk_mul), compare order x-then-y per
// pair == exact q order, strict > keeps first max; q=0 always valid
// (deg>=1), valid entries strictly positive -> zero slots never win.
// cost = ln(T[best]) via __logf (roundtrip ~5e-6 << bf16 granularity).
// Tail: ONE barrier — wave max via shfl butterfly, wave sum via DPP
// shr/bcast tree (lane 63 writes); block combine ssum[w]*exp(smax[w]-bm);
// each pair's v appears twice -> *0.5.
// ---------------------------------------------------------------------------
__global__ __launch_bounds__(256, 4) void fused_kernel(
    const float* __restrict__ xs, const float* __restrict__ xt,
    const int* __restrict__ dst_s, const int* __restrict__ dst_t,
    float* __restrict__ out)
{
    __shared__ float  ssim[NN];              // self sim row (for epilogue)
    __shared__ float  ecol[NN + 1][20];      // transposed exp rows; col NN zero
    __shared__ float4 xsl[DEG + 1][NC / 4];
    __shared__ float  smax[4], ssum[4];

    const int bi  = blockIdx.x;
    const int b   = bi >> 7, i = bi & 127;
    const int tid = threadIdx.x;
    const int gs  = b * NN + i;

    // ---- s-side neighbor mask (block-uniform) ----
    unsigned long long slo = 0ull, shi = 0ull;
    #pragma unroll
    for (int k = 0; k < DEG; ++k) {
        int d = dst_s[gs * DEG + k] & (NN - 1);
        if (d < 64) slo |= 1ull << d; else shi |= 1ull << (d - 64);
    }
    const int dsi = __popcll(slo) + __popcll(shi);

    // ---- sim-phase mapping: quarter-row, two columns per thread (packed) ----
    const int qh = tid & 3;                  // quarter id
    const int jp = tid >> 2;                 // column pair 0..63
    const int c0 = 2 * jp;                   // owned columns c0, c0+1
    v2f xvp[16];
    {
        const float4* xt0 = (const float4*)(xt + (size_t)(b * NN + c0)     * NC) + qh * 4;
        const float4* xt1 = (const float4*)(xt + (size_t)(b * NN + c0 + 1) * NC) + qh * 4;
        #pragma unroll
        for (int k = 0; k < 4; ++k) {
            float4 u = xt0[k], w = xt1[k];
            xvp[4 * k + 0] = mk2(u.x, w.x);
            xvp[4 * k + 1] = mk2(u.y, w.y);
            xvp[4 * k + 2] = mk2(u.z, w.z);
            xvp[4 * k + 3] = mk2(u.w, w.w);
        }
    }

    // ---- zero column of ecol (slots 0..12 cover all read slots) ----
    if (tid < 13) ecol[NN][tid] = 0.0f;

    // ---- stage x_s rows into LDS: threads 0..175, row = tid>>4, k = tid&15 ----
    if (tid < (DEG + 1) * 16) {
        int r = tid >> 4, k = tid & 15;
        int node = i;                        // r==10 -> self row
        if (r < DEG) {
            unsigned long long lo = slo, hi = shi; int sel = 0;
            #pragma unroll
            for (int q = 0; q < DEG; ++q) {  // static walk, scalar select
                int t;
                if (lo)      { t = __builtin_ctzll(lo);      lo &= lo - 1ull; }
                else if (hi) { t = 64 + __builtin_ctzll(hi); hi &= hi - 1ull; }
                else t = 0;
                if (q == r) sel = t;
            }
            node = sel;
        }
        if (r == DEG || r < dsi)
            xsl[r][k] = ((const float4*)(xs + (size_t)(b * NN + node) * NC))[k];
    }

    // ---- t-side neighbor list for sinkhorn pair j = tid>>1 (int2 loads) ----
    const int j = tid >> 1, h = tid & 1;
    const int gt = b * NN + j;
    unsigned long long tlo = 0ull, thi = 0ull;
    {
        const int2* dt2 = (const int2*)(dst_t + (size_t)gt * DEG);  // 40B rows, 8B-aligned
        int2 w0 = dt2[0], w1 = dt2[1], w2 = dt2[2], w3 = dt2[3], w4 = dt2[4];
        int dd[DEG] = { w0.x, w0.y, w1.x, w1.y, w2.x, w2.y, w3.x, w3.y, w4.x, w4.y };
        #pragma unroll
        for (int k = 0; k < DEG; ++k) {      // static-indexed reads of dd
            int dm = dd[k] & (NN - 1);
            if (dm < 64) tlo |= 1ull << dm; else thi |= 1ull << (dm - 64);
        }
    }
    const int dtj = __popcll(tlo) + __popcll(thi);
    int ntq[DEG];
    {
        unsigned long long lo = tlo, hi = thi;
        #pragma unroll
        for (int q = 0; q < DEG; ++q) {      // static-indexed writes
            int t;
            if (lo)      { t = __builtin_ctzll(lo);      lo &= lo - 1ull; }
            else if (hi) { t = 64 + __builtin_ctzll(hi); hi &= hi - 1ull; }
            else t = 0;
            ntq[q] = (q < dtj) ? t : NN;     // invalid -> zero column
        }
    }
    __syncthreads();

    // ---- sim dots: 4 xsl-quarter broadcast reads/row, 16 packed FMAs ----
    #pragma unroll
    for (int r = 0; r <= DEG; ++r) {
        if (r == DEG || r < dsi) {           // wave-uniform (dsi block-uniform)
            v2f acc = mk2(0.f, 0.f);
            #pragma unroll
            for (int k = 0; k < 4; ++k) {
                float4 s4 = xsl[r][qh * 4 + k];
                acc = pfma(splat2(s4.x), xvp[4 * k + 0], acc);
                acc = pfma(splat2(s4.y), xvp[4 * k + 1], acc);
                acc = pfma(splat2(s4.z), xvp[4 * k + 2], acc);
                acc = pfma(splat2(s4.w), xvp[4 * k + 3], acc);
            }
            float a0 = acc.x, a1 = acc.y;
            // 4-lane butterfly: all lanes end with the full deterministic sum
            a0 += pswap(a0);  a0 += pswap2(a0);
            a1 += pswap(a1);  a1 += pswap2(a1);
            float vv = (qh & 1) ? a1 : a0;
            int   cc = c0 + (qh & 1);
            if (qh < 2) {
                if (r < DEG) ecol[cc][r + ((r >= HP) ? 3 : 0)] = __expf(vv);
                else         ssim[cc] = vv;
            }
        } else {
            if (qh < 2) ecol[c0 + (qh & 1)][r + ((r >= HP) ? 3 : 0)] = 0.0f;
        }
    }
    __syncthreads();

    // ---- gather own half of T, packed by q-pairs straight from LDS ----
    v2f T2[HP][5];                           // T2[pp][qq] = (T[pp][2qq], T[pp][2qq+1])
    float a[HP];
    v2f bv2[5];
    #pragma unroll
    for (int qq = 0; qq < 5; ++qq)
        bv2[qq] = mk2((2 * qq < dtj) ? 1.0f : 0.0f, (2 * qq + 1 < dtj) ? 1.0f : 0.0f);

    const int sbase = h << 3;                // h=0 -> slots 0..4; h=1 -> 8..12
    #pragma unroll
    for (int qq = 0; qq < 5; ++qq) {
        const float* cp0 = &ecol[ntq[2 * qq]][sbase];
        const float* cp1 = &ecol[ntq[2 * qq + 1]][sbase];
        float4 A4 = *(const float4*)cp0;     // ds_read_b128
        float  Ae = cp0[4];                  // ds_read_b32
        float4 B4 = *(const float4*)cp1;
        float  Be = cp1[4];
        T2[0][qq] = mk2(A4.x, B4.x);
        T2[1][qq] = mk2(A4.y, B4.y);
        T2[2][qq] = mk2(A4.z, B4.z);
        T2[3][qq] = mk2(A4.w, B4.w);
        T2[4][qq] = mk2(Ae,   Be);
    }
    #pragma unroll
    for (int pp = 0; pp < HP; ++pp) {
        int p = h * HP + pp;
        v2f s01 = T2[pp][0] + T2[pp][1];
        v2f s23 = T2[pp][2] + T2[pp][3];
        v2f s   = (s01 + s23) + T2[pp][4];
        float sum = s.x + s.y;
        a[pp] = (p < dsi) ? __builtin_amdgcn_rcpf(sum) * 10.0f : 0.0f;
    }

    // ---- Sinkhorn: 4 x (col + row) + final col (last row phase is dead) ----
#define COL_PHASE()                                                            \
    {                                                                          \
        _Pragma("unroll")                                                      \
        for (int qq = 0; qq < 5; ++qq) {                                       \
            v2f cA = pfma(splat2(a[2]), T2[2][qq],                             \
                      pfma(splat2(a[1]), T2[1][qq], T2[0][qq] * splat2(a[0])));\
            v2f cB = pfma(splat2(a[4]), T2[4][qq], T2[3][qq] * splat2(a[3]));  \
            v2f c  = cA + cB;                                                  \
            float cx = c.x + pswap(c.x);     /* identical on both lanes */     \
            float cy = c.y + pswap(c.y);                                       \
            float b0 = bv2[qq].x, b1 = bv2[qq].y;                              \
            /* masked q: b==0 -> 0 * rcp(1e-8) == 0 exactly */                 \
            bv2[qq].x = b0 * __builtin_amdgcn_rcpf(fmaf(b0, cx, 1e-8f));       \
            bv2[qq].y = b1 * __builtin_amdgcn_rcpf(fmaf(b1, cy, 1e-8f));       \
        }                                                                      \
    }

    #pragma unroll 1
    for (int it = 0; it < NUM_STEPS - 1; ++it) {
        COL_PHASE()
        // row phase: packed q-pair chains + horizontal add
        #pragma unroll
        for (int pp = 0; pp < HP; ++pp) {
            v2f r1 = pfma(T2[pp][1], bv2[1], T2[pp][0] * bv2[0]);
            v2f r2 = pfma(T2[pp][3], bv2[3], T2[pp][2] * bv2[2]);
            v2f rr = pfma(T2[pp][4], bv2[4], r1 + r2);
            float r = rr.x + rr.y;
            float ap = a[pp];
            // masked row: ap==0 and r==0 -> 0 * rcp(1e-8) == 0 exactly
            a[pp] = ap * __builtin_amdgcn_rcpf(fmaf(ap, r, 1e-8f));
        }
    }
    COL_PHASE()                               // 5th col; 5th row phase dead
#undef COL_PHASE

    // ---- argmax per own row over T*b (packed muls, exact q order) ----
    float cpart = 0.f;
    #pragma unroll
    for (int pp = 0; pp < HP; ++pp) {
        int p = h * HP + pp;
        if (p < dsi) {
            v2f pr0 = T2[pp][0] * bv2[0];
            v2f pr1 = T2[pp][1] * bv2[1];
            v2f pr2 = T2[pp][2] * bv2[2];
            v2f pr3 = T2[pp][3] * bv2[3];
            v2f pr4 = T2[pp][4] * bv2[4];
            float best = pr0.x;               // q=0 always valid (deg>=1)
            float bT   = T2[pp][0].x;
            if (pr0.y > best) { best = pr0.y; bT = T2[pp][0].y; }
            if (pr1.x > best) { best = pr1.x; bT = T2[pp][1].x; }
            if (pr1.y > best) { best = pr1.y; bT = T2[pp][1].y; }
            if (pr2.x > best) { best = pr2.x; bT = T2[pp][2].x; }
            if (pr2.y > best) { best = pr2.y; bT = T2[pp][2].y; }
            if (pr3.x > best) { best = pr3.x; bT = T2[pp][3].x; }
            if (pr3.y > best) { best = pr3.y; bT = T2[pp][3].y; }
            if (pr4.x > best) { best = pr4.x; bT = T2[pp][4].x; }
            if (pr4.y > best) { best = pr4.y; bT = T2[pp][4].y; }
            cpart += __logf(bT);              // == sim value (roundtrip ~5e-6)
        }
    }
    float cost = cpart + pswap(cpart);           // identical on both lanes

    float M = (float)((dsi > dtj) ? dsi : dtj);
    float simv = ssim[j];
    float v = fmaf(cost, __builtin_amdgcn_rcpf(1.0f + M), simv);

    // ---- one-barrier block softmax over j (each pair's v counted twice) ----
    float wm = v;                                // wave max: all lanes need it
    #pragma unroll
    for (int off = 32; off; off >>= 1) wm = fmaxf(wm, __shfl_xor(wm, off));
    float ew = __expf(v - wm);
    // wave sum via DPP tree (0-fill OOB); total lands on lane 63
    float ws = ew;
    ws += dpp0<0x111>(ws);                       // row_shr:1
    ws += dpp0<0x112>(ws);                       // row_shr:2
    ws += dpp0<0x114>(ws);                       // row_shr:4
    ws += dpp0<0x118>(ws);                       // row_shr:8
    ws += dpp0<0x142>(ws);                       // row_bcast15
    ws += dpp0<0x143>(ws);                       // row_bcast31
    int wsl = tid >> 6;
    if ((tid & 63) == 63) { smax[wsl] = wm; ssum[wsl] = ws; }
    __syncthreads();
    float bm = fmaxf(fmaxf(smax[0], smax[1]), fmaxf(smax[2], smax[3]));
    float bs = (ssum[0] * __expf(smax[0] - bm) + ssum[1] * __expf(smax[1] - bm) +
                ssum[2] * __expf(smax[2] - bm) + ssum[3] * __expf(smax[3] - bm)) * 0.5f;
    float e = ew * __expf(wm - bm);

    if (h == 0) out[(size_t)gs * NN + j] = e * __builtin_amdgcn_rcpf(bs);
}

// ---------------------------------------------------------------------------
extern "C" void kernel_launch(void* const* d_in, const int* in_sizes, int n_in,
                              void* d_out, int out_size, void* d_ws, size_t ws_size,
                              hipStream_t stream) {
    (void)in_sizes; (void)n_in; (void)out_size; (void)d_ws; (void)ws_size;
    const float* x_s  = (const float*)d_in[0];
    const int*   ei_s = (const int*)  d_in[1];
    const float* x_t  = (const float*)d_in[3];
    const int*   ei_t = (const int*)  d_in[4];
    float* out = (float*)d_out;

    const int* dst_s = ei_s + NB * NN * DEG;   // second row of edge_index
    const int* dst_t = ei_t + NB * NN * DEG;

    hipLaunchKernelGGL(fused_kernel, dim3(NB * NN), dim3(256), 0, stream,
                       x_s, x_t, dst_s, dst_t, out);
}